// Round 3
// baseline (154.543 us; speedup 1.0000x reference)
//
#include <hip/hip_runtime.h>

#define PP 50
#define TPB 256
#define NBATCH 2048
#define NCOPY 64   // contention-spreading copies for stat atomics

static constexpr float EPSF = 1e-5f;
static constexpr double ETOT = 5120000.0;   // B * P * P

static __device__ __forceinline__ float lrelu(float x) {
    return fmaxf(x, 0.0f) + 0.01f * fminf(x, 0.0f);
}
// Pin a wave-uniform float into an SGPR (weights, BN scale/shift): keeps the
// inner loop free of LDS re-reads and costs zero VGPRs.
static __device__ __forceinline__ float rfl(float x) {
    return __int_as_float(__builtin_amdgcn_readfirstlane(__float_as_int(x)));
}

// acc layout in d_ws (doubles):
//   acc1[s*64 + c]  s in 0..9  (sum:0-4, sumsq:5-9)   offset 0,   640 doubles
//   acc2[s*64 + c]  s in 0..9                          offset 640, 640 doubles

// ---------------- Pass 1: y1 = mlp_in @ W1^T + b1 ; accumulate sum/sumsq ----
__global__ __launch_bounds__(TPB) void pass1_kernel(
    const float* __restrict__ feat, const float* __restrict__ ang,
    const float* __restrict__ W1, const float* __restrict__ b1,
    double* __restrict__ acc)
{
    __shared__ float4 nd[PP];
    __shared__ float red[4][10];
    const int t = threadIdx.x;
    const int base = blockIdx.x * PP;

    if (t < PP) {
        float f  = feat[base + t];
        float br = ang[2*(base+t)];
        float bi = ang[2*(base+t)+1];
        nd[t] = make_float4(f, br, bi, 1.0f / (br*br + bi*bi));
    }

    float w1[25], bb1[5];
#pragma unroll
    for (int i = 0; i < 25; ++i) w1[i] = rfl(W1[i]);
#pragma unroll
    for (int i = 0; i < 5; ++i)  bb1[i] = rfl(b1[i]);

    __syncthreads();

    float a[10];
#pragma unroll
    for (int k = 0; k < 10; ++k) a[k] = 0.0f;

    if (t < 250) {
        const int pi = t / 5;
        const int s  = t - pi*5;
        const float4 ni = nd[pi];
        const float fi = ni.x, ar = ni.y, ai = ni.z;
#pragma unroll
        for (int q = 0; q < 10; ++q) {
            const float4 nj = nd[s*10 + q];
            const float fj = nj.x, br = nj.y, bi = nj.z, inv = nj.w;
            const float dr = (ar*br + ai*bi) * inv;
            const float dm = (ai*br - ar*bi) * inv;
            const float df = fj - fi;
#pragma unroll
            for (int o = 0; o < 5; ++o) {
                float y = bb1[o];
                y = fmaf(w1[o*5+0], fi, y);
                y = fmaf(w1[o*5+1], fj, y);
                y = fmaf(w1[o*5+2], df, y);
                y = fmaf(w1[o*5+3], dr, y);
                y = fmaf(w1[o*5+4], dm, y);
                a[o]   += y;
                a[5+o]  = fmaf(y, y, a[5+o]);
            }
        }
    }

#pragma unroll
    for (int k = 0; k < 10; ++k) {
        float v = a[k];
#pragma unroll
        for (int off = 32; off > 0; off >>= 1) v += __shfl_down(v, off, 64);
        a[k] = v;
    }
    const int lane = t & 63, wv = t >> 6;
    if (lane == 0) {
#pragma unroll
        for (int k = 0; k < 10; ++k) red[wv][k] = a[k];
    }
    __syncthreads();
    if (t < 10) {
        atomicAdd(&acc[t * NCOPY + (blockIdx.x & (NCOPY-1))],
                  (double)(red[0][t] + red[1][t] + red[2][t] + red[3][t]));
    }
}

// ---------------- Pass 2: h1 = lrelu(BN1(y1)); y2 = h1 @ W2^T + b2 ; stats --
__global__ __launch_bounds__(TPB) void pass2_kernel(
    const float* __restrict__ feat, const float* __restrict__ ang,
    const float* __restrict__ W1, const float* __restrict__ b1,
    const float* __restrict__ g1, const float* __restrict__ bt1,
    const float* __restrict__ W2, const float* __restrict__ b2,
    double* __restrict__ acc)
{
    __shared__ float4 nd[PP];
    __shared__ double tmp[10];
    __shared__ float red[4][10];
    const int t = threadIdx.x;
    const int base = blockIdx.x * PP;

    if (t < PP) {
        float f  = feat[base + t];
        float br = ang[2*(base+t)];
        float bi = ang[2*(base+t)+1];
        nd[t] = make_float4(f, br, bi, 1.0f / (br*br + bi*bi));
    }
    if (t >= 64 && t < 74) {   // separate wave from nd staging; any 10 threads work
        const int k = t - 64;
        double s = 0.0;
#pragma unroll
        for (int c = 0; c < NCOPY; ++c) s += acc[k * NCOPY + c];
        tmp[k] = s;
    }

    float w1[25], bb1[5], w2[25], bb2[5];
#pragma unroll
    for (int i = 0; i < 25; ++i) { w1[i] = rfl(W1[i]); w2[i] = rfl(W2[i]); }
#pragma unroll
    for (int i = 0; i < 5; ++i)  { bb1[i] = rfl(b1[i]); bb2[i] = rfl(b2[i]); }

    __syncthreads();

    // uniform BN1 fold -> SGPRs (computed redundantly by every thread)
    float sc1[5], sh1[5];
#pragma unroll
    for (int o = 0; o < 5; ++o) {
        double mu  = tmp[o]   / ETOT;
        double var = tmp[5+o] / ETOT - mu * mu;
        float s = rfl(g1[o]) * rsqrtf((float)var + EPSF);
        sc1[o] = rfl(s);
        sh1[o] = rfl(rfl(bt1[o]) - (float)mu * s);
    }

    float a[10];
#pragma unroll
    for (int k = 0; k < 10; ++k) a[k] = 0.0f;

    if (t < 250) {
        const int pi = t / 5;
        const int s  = t - pi*5;
        const float4 ni = nd[pi];
        const float fi = ni.x, ar = ni.y, ai = ni.z;
#pragma unroll
        for (int q = 0; q < 10; ++q) {
            const float4 nj = nd[s*10 + q];
            const float fj = nj.x, br = nj.y, bi = nj.z, inv = nj.w;
            const float dr = (ar*br + ai*bi) * inv;
            const float dm = (ai*br - ar*bi) * inv;
            const float df = fj - fi;
            float h1[5];
#pragma unroll
            for (int o = 0; o < 5; ++o) {
                float y = bb1[o];
                y = fmaf(w1[o*5+0], fi, y);
                y = fmaf(w1[o*5+1], fj, y);
                y = fmaf(w1[o*5+2], df, y);
                y = fmaf(w1[o*5+3], dr, y);
                y = fmaf(w1[o*5+4], dm, y);
                h1[o] = lrelu(fmaf(y, sc1[o], sh1[o]));
            }
#pragma unroll
            for (int o = 0; o < 5; ++o) {
                float y = bb2[o];
                y = fmaf(w2[o*5+0], h1[0], y);
                y = fmaf(w2[o*5+1], h1[1], y);
                y = fmaf(w2[o*5+2], h1[2], y);
                y = fmaf(w2[o*5+3], h1[3], y);
                y = fmaf(w2[o*5+4], h1[4], y);
                a[o]   += y;
                a[5+o]  = fmaf(y, y, a[5+o]);
            }
        }
    }

#pragma unroll
    for (int k = 0; k < 10; ++k) {
        float v = a[k];
#pragma unroll
        for (int off = 32; off > 0; off >>= 1) v += __shfl_down(v, off, 64);
        a[k] = v;
    }
    const int lane = t & 63, wv = t >> 6;
    if (lane == 0) {
#pragma unroll
        for (int k = 0; k < 10; ++k) red[wv][k] = a[k];
    }
    __syncthreads();
    if (t < 10) {
        atomicAdd(&acc[(10 + t) * NCOPY + (blockIdx.x & (NCOPY-1))],
                  (double)(red[0][t] + red[1][t] + red[2][t] + red[3][t]));
    }
}

// ---- Pass 3: full MLP, mean-aggregate y3 per dst, rotate, write output -----
__global__ __launch_bounds__(TPB) void pass3_kernel(
    const float* __restrict__ pt,
    const float* __restrict__ feat, const float* __restrict__ ang,
    const float* __restrict__ W1, const float* __restrict__ b1,
    const float* __restrict__ g1, const float* __restrict__ bt1,
    const float* __restrict__ W2, const float* __restrict__ b2,
    const float* __restrict__ g2, const float* __restrict__ bt2,
    const float* __restrict__ W3, const float* __restrict__ b3,
    const double* __restrict__ acc, float* __restrict__ out)
{
    __shared__ float4 nd[PP];
    __shared__ float spt[PP];
    __shared__ double tmp[20];
    __shared__ float part[250][5];
    const int t = threadIdx.x;
    const int base = blockIdx.x * PP;

    if (t < PP) {
        float f  = feat[base + t];
        float br = ang[2*(base+t)];
        float bi = ang[2*(base+t)+1];
        nd[t] = make_float4(f, br, bi, 1.0f / (br*br + bi*bi));
        spt[t] = pt[base + t];
    }
    if (t >= 64 && t < 84) {
        const int k = t - 64;
        double s = 0.0;
#pragma unroll
        for (int c = 0; c < NCOPY; ++c) s += acc[k * NCOPY + c];
        tmp[k] = s;
    }

    float w1[25], bb1[5], w2[25], bb2[5], w3[25], bb3[5];
#pragma unroll
    for (int i = 0; i < 25; ++i) {
        w1[i] = rfl(W1[i]); w2[i] = rfl(W2[i]); w3[i] = rfl(W3[i]);
    }
#pragma unroll
    for (int i = 0; i < 5; ++i) {
        bb1[i] = rfl(b1[i]); bb2[i] = rfl(b2[i]); bb3[i] = rfl(b3[i]);
    }

    __syncthreads();

    float sc1[5], sh1[5], sc2[5], sh2[5];
#pragma unroll
    for (int o = 0; o < 5; ++o) {
        double mu1  = tmp[o]    / ETOT;
        double var1 = tmp[5+o]  / ETOT - mu1 * mu1;
        float s1 = rfl(g1[o]) * rsqrtf((float)var1 + EPSF);
        sc1[o] = rfl(s1);
        sh1[o] = rfl(rfl(bt1[o]) - (float)mu1 * s1);
        double mu2  = tmp[10+o] / ETOT;
        double var2 = tmp[15+o] / ETOT - mu2 * mu2;
        float s2 = rfl(g2[o]) * rsqrtf((float)var2 + EPSF);
        sc2[o] = rfl(s2);
        sh2[o] = rfl(rfl(bt2[o]) - (float)mu2 * s2);
    }

    float a[5];
#pragma unroll
    for (int k = 0; k < 5; ++k) a[k] = 0.0f;

    if (t < 250) {
        const int pi = t / 5;
        const int s  = t - pi*5;
        const float4 ni = nd[pi];
        const float fi = ni.x, ar = ni.y, ai = ni.z;
#pragma unroll
        for (int q = 0; q < 10; ++q) {
            const float4 nj = nd[s*10 + q];
            const float fj = nj.x, br = nj.y, bi = nj.z, inv = nj.w;
            const float dr = (ar*br + ai*bi) * inv;
            const float dm = (ai*br - ar*bi) * inv;
            const float df = fj - fi;
            float h1[5], h2[5];
#pragma unroll
            for (int o = 0; o < 5; ++o) {
                float y = bb1[o];
                y = fmaf(w1[o*5+0], fi, y);
                y = fmaf(w1[o*5+1], fj, y);
                y = fmaf(w1[o*5+2], df, y);
                y = fmaf(w1[o*5+3], dr, y);
                y = fmaf(w1[o*5+4], dm, y);
                h1[o] = lrelu(fmaf(y, sc1[o], sh1[o]));
            }
#pragma unroll
            for (int o = 0; o < 5; ++o) {
                float y = bb2[o];
                y = fmaf(w2[o*5+0], h1[0], y);
                y = fmaf(w2[o*5+1], h1[1], y);
                y = fmaf(w2[o*5+2], h1[2], y);
                y = fmaf(w2[o*5+3], h1[3], y);
                y = fmaf(w2[o*5+4], h1[4], y);
                h2[o] = lrelu(fmaf(y, sc2[o], sh2[o]));
            }
#pragma unroll
            for (int o = 0; o < 5; ++o) {
                float y = bb3[o];
                y = fmaf(w3[o*5+0], h2[0], y);
                y = fmaf(w3[o*5+1], h2[1], y);
                y = fmaf(w3[o*5+2], h2[2], y);
                y = fmaf(w3[o*5+3], h2[3], y);
                y = fmaf(w3[o*5+4], h2[4], y);
                a[o] += y;
            }
        }
    }

    if (t < 250) {
#pragma unroll
        for (int c = 0; c < 5; ++c) part[t][c] = a[c];
    }
    __syncthreads();

    if (t < PP) {
        float m[5];
#pragma unroll
        for (int c = 0; c < 5; ++c) {
            m[c] = (part[5*t][c] + part[5*t+1][c] + part[5*t+2][c] +
                    part[5*t+3][c] + part[5*t+4][c]) * 0.02f;
        }
        const int d = base + t;
        const float4 ni = nd[t];
        const float zr = ni.y, zi = ni.z;
        float ss, cc;
        sincosf(6.2831853071795865f * m[4], &ss, &cc);
        float* o = out + (size_t)d * 7;
        o[0] = spt[t];
        o[1] = m[0];
        o[2] = m[1];
        o[3] = m[2];
        o[4] = m[3];
        o[5] = cc * zr - ss * zi;
        o[6] = cc * zi + ss * zr;
    }
}

extern "C" void kernel_launch(void* const* d_in, const int* in_sizes, int n_in,
                              void* d_out, int out_size, void* d_ws, size_t ws_size,
                              hipStream_t stream)
{
    const float* pt   = (const float*)d_in[0];
    const float* feat = (const float*)d_in[1];
    const float* ang  = (const float*)d_in[2];
    const float* W1   = (const float*)d_in[3];
    const float* b1   = (const float*)d_in[4];
    const float* g1   = (const float*)d_in[5];
    const float* bt1  = (const float*)d_in[6];
    const float* W2   = (const float*)d_in[7];
    const float* b2   = (const float*)d_in[8];
    const float* g2   = (const float*)d_in[9];
    const float* bt2  = (const float*)d_in[10];
    const float* W3   = (const float*)d_in[11];
    const float* b3   = (const float*)d_in[12];
    // d_in[13] = edge_index: structure is closed-form (dst=b*P+pi, src=b*P+pj), unused.
    float* out  = (float*)d_out;
    double* acc = (double*)d_ws;   // 1280 doubles: [0..640) pass1 stats, [640..1280) pass2

    hipMemsetAsync(d_ws, 0, 1280 * sizeof(double), stream);
    pass1_kernel<<<NBATCH, TPB, 0, stream>>>(feat, ang, W1, b1, acc);
    pass2_kernel<<<NBATCH, TPB, 0, stream>>>(feat, ang, W1, b1, g1, bt1, W2, b2, acc);
    pass3_kernel<<<NBATCH, TPB, 0, stream>>>(pt, feat, ang, W1, b1, g1, bt1, W2, b2,
                                             g2, bt2, W3, b3, acc, out);
}

// Round 4
// 146.516 us; speedup vs baseline: 1.0548x; 1.0548x over previous
//
#include <hip/hip_runtime.h>

#define PP 50
#define TPB 256
#define NBATCH 2048
#define GB 2                    // batches per block
#define NBLK (NBATCH / GB)      // 1024 blocks
#define NCOPY 64                // contention-spreading copies for stat atomics

static constexpr float EPSF = 1e-5f;
static constexpr double INV_ETOT = 1.0 / 5120000.0;   // 1 / (B*P*P)

static __device__ __forceinline__ float lrelu(float x) {
    return fmaxf(x, 0.0f) + 0.01f * fminf(x, 0.0f);
}
static __device__ __forceinline__ float rfl(float x) {
    return __int_as_float(__builtin_amdgcn_readfirstlane(__float_as_int(x)));
}

// acc layout in d_ws (doubles): acc[(slot)*64 + copy], slots 0..9 pass1 (sum 0-4,
// sumsq 5-9), slots 10..19 pass2. 1280 doubles total.

// ---------------- Pass 1: y1 = mlp_in @ W1^T + b1 ; accumulate sum/sumsq ----
__global__ __launch_bounds__(TPB) void pass1_kernel(
    const float* __restrict__ feat, const float* __restrict__ ang,
    const float* __restrict__ W1, const float* __restrict__ b1,
    double* __restrict__ acc)
{
    __shared__ float4 nd[GB][PP];
    __shared__ float red[4][10];
    const int t = threadIdx.x;

    // stage both batches in parallel (different waves)
    if (t < PP) {
        const int idx = blockIdx.x * GB * PP + t;
        float f  = feat[idx];
        float br = ang[2*idx], bi = ang[2*idx+1];
        nd[0][t] = make_float4(f, br, bi, 1.0f / (br*br + bi*bi));
    } else if (t >= 64 && t < 64 + PP) {
        const int idx = blockIdx.x * GB * PP + PP + (t - 64);
        float f  = feat[idx];
        float br = ang[2*idx], bi = ang[2*idx+1];
        nd[1][t-64] = make_float4(f, br, bi, 1.0f / (br*br + bi*bi));
    }

    float w1[25], bb1[5];
#pragma unroll
    for (int i = 0; i < 25; ++i) w1[i] = rfl(W1[i]);
#pragma unroll
    for (int i = 0; i < 5; ++i)  bb1[i] = rfl(b1[i]);

    __syncthreads();

    float a[10];
#pragma unroll
    for (int k = 0; k < 10; ++k) a[k] = 0.0f;

    if (t < 250) {
        const int pi = t / 5;
        const int s  = t - pi*5;
#pragma unroll
        for (int g = 0; g < GB; ++g) {
            const float4 ni = nd[g][pi];
            const float fi = ni.x, ar = ni.y, ai = ni.z;
#pragma unroll
            for (int q = 0; q < 10; ++q) {
                const float4 nj = nd[g][s*10 + q];
                const float fj = nj.x, br = nj.y, bi = nj.z, inv = nj.w;
                const float dr = (ar*br + ai*bi) * inv;
                const float dm = (ai*br - ar*bi) * inv;
                const float df = fj - fi;
#pragma unroll
                for (int o = 0; o < 5; ++o) {
                    float y = bb1[o];
                    y = fmaf(w1[o*5+0], fi, y);
                    y = fmaf(w1[o*5+1], fj, y);
                    y = fmaf(w1[o*5+2], df, y);
                    y = fmaf(w1[o*5+3], dr, y);
                    y = fmaf(w1[o*5+4], dm, y);
                    a[o]   += y;
                    a[5+o]  = fmaf(y, y, a[5+o]);
                }
            }
        }
    }

#pragma unroll
    for (int k = 0; k < 10; ++k) {
        float v = a[k];
#pragma unroll
        for (int off = 32; off > 0; off >>= 1) v += __shfl_down(v, off, 64);
        a[k] = v;
    }
    const int lane = t & 63, wv = t >> 6;
    if (lane == 0) {
#pragma unroll
        for (int k = 0; k < 10; ++k) red[wv][k] = a[k];
    }
    __syncthreads();
    if (t < 10) {
        atomicAdd(&acc[t * NCOPY + (blockIdx.x & (NCOPY-1))],
                  (double)(red[0][t] + red[1][t] + red[2][t] + red[3][t]));
    }
}

// ---------------- Pass 2: h1 = lrelu(BN1(y1)); y2 = h1 @ W2^T + b2 ; stats --
__global__ __launch_bounds__(TPB) void pass2_kernel(
    const float* __restrict__ feat, const float* __restrict__ ang,
    const float* __restrict__ W1, const float* __restrict__ b1,
    const float* __restrict__ g1, const float* __restrict__ bt1,
    const float* __restrict__ W2, const float* __restrict__ b2,
    double* __restrict__ acc)
{
    __shared__ float4 nd[GB][PP];
    __shared__ double tmp[10];
    __shared__ float red[4][10];
    const int t = threadIdx.x;

    if (t < PP) {
        const int idx = blockIdx.x * GB * PP + t;
        float f  = feat[idx];
        float br = ang[2*idx], bi = ang[2*idx+1];
        nd[0][t] = make_float4(f, br, bi, 1.0f / (br*br + bi*bi));
    } else if (t >= 64 && t < 64 + PP) {
        const int idx = blockIdx.x * GB * PP + PP + (t - 64);
        float f  = feat[idx];
        float br = ang[2*idx], bi = ang[2*idx+1];
        nd[1][t-64] = make_float4(f, br, bi, 1.0f / (br*br + bi*bi));
    } else if (t >= 128 && t < 138) {
        const int k = t - 128;
        double s = 0.0;
#pragma unroll
        for (int c = 0; c < NCOPY; ++c) s += acc[k * NCOPY + c];
        tmp[k] = s;
    }

    float w1[25], bb1[5], w2[25], bb2[5];
#pragma unroll
    for (int i = 0; i < 25; ++i) { w1[i] = rfl(W1[i]); w2[i] = rfl(W2[i]); }
#pragma unroll
    for (int i = 0; i < 5; ++i)  { bb1[i] = rfl(b1[i]); bb2[i] = rfl(b2[i]); }

    __syncthreads();

    // uniform BN1 fold (f64 multiplies only — no microcoded divides)
    float sc1[5], sh1[5];
#pragma unroll
    for (int o = 0; o < 5; ++o) {
        double mu  = tmp[o]   * INV_ETOT;
        double var = tmp[5+o] * INV_ETOT - mu * mu;
        float s = rfl(g1[o]) * rsqrtf((float)var + EPSF);
        sc1[o] = rfl(s);
        sh1[o] = rfl(rfl(bt1[o]) - (float)mu * s);
    }

    float a[10];
#pragma unroll
    for (int k = 0; k < 10; ++k) a[k] = 0.0f;

    if (t < 250) {
        const int pi = t / 5;
        const int s  = t - pi*5;
#pragma unroll
        for (int g = 0; g < GB; ++g) {
            const float4 ni = nd[g][pi];
            const float fi = ni.x, ar = ni.y, ai = ni.z;
#pragma unroll
            for (int q = 0; q < 10; ++q) {
                const float4 nj = nd[g][s*10 + q];
                const float fj = nj.x, br = nj.y, bi = nj.z, inv = nj.w;
                const float dr = (ar*br + ai*bi) * inv;
                const float dm = (ai*br - ar*bi) * inv;
                const float df = fj - fi;
                float h1[5];
#pragma unroll
                for (int o = 0; o < 5; ++o) {
                    float y = bb1[o];
                    y = fmaf(w1[o*5+0], fi, y);
                    y = fmaf(w1[o*5+1], fj, y);
                    y = fmaf(w1[o*5+2], df, y);
                    y = fmaf(w1[o*5+3], dr, y);
                    y = fmaf(w1[o*5+4], dm, y);
                    h1[o] = lrelu(fmaf(y, sc1[o], sh1[o]));
                }
#pragma unroll
                for (int o = 0; o < 5; ++o) {
                    float y = bb2[o];
                    y = fmaf(w2[o*5+0], h1[0], y);
                    y = fmaf(w2[o*5+1], h1[1], y);
                    y = fmaf(w2[o*5+2], h1[2], y);
                    y = fmaf(w2[o*5+3], h1[3], y);
                    y = fmaf(w2[o*5+4], h1[4], y);
                    a[o]   += y;
                    a[5+o]  = fmaf(y, y, a[5+o]);
                }
            }
        }
    }

#pragma unroll
    for (int k = 0; k < 10; ++k) {
        float v = a[k];
#pragma unroll
        for (int off = 32; off > 0; off >>= 1) v += __shfl_down(v, off, 64);
        a[k] = v;
    }
    const int lane = t & 63, wv = t >> 6;
    if (lane == 0) {
#pragma unroll
        for (int k = 0; k < 10; ++k) red[wv][k] = a[k];
    }
    __syncthreads();
    if (t < 10) {
        atomicAdd(&acc[(10 + t) * NCOPY + (blockIdx.x & (NCOPY-1))],
                  (double)(red[0][t] + red[1][t] + red[2][t] + red[3][t]));
    }
}

// ---- Pass 3: full MLP, mean-aggregate y3 per dst, rotate, write output -----
__global__ __launch_bounds__(TPB) void pass3_kernel(
    const float* __restrict__ pt,
    const float* __restrict__ feat, const float* __restrict__ ang,
    const float* __restrict__ W1, const float* __restrict__ b1,
    const float* __restrict__ g1, const float* __restrict__ bt1,
    const float* __restrict__ W2, const float* __restrict__ b2,
    const float* __restrict__ g2, const float* __restrict__ bt2,
    const float* __restrict__ W3, const float* __restrict__ b3,
    const double* __restrict__ acc, float* __restrict__ out)
{
    __shared__ float4 nd[GB][PP];
    __shared__ float spt[GB][PP];
    __shared__ double tmp[20];
    __shared__ float part[250][5];
    const int t = threadIdx.x;

    if (t < PP) {
        const int idx = blockIdx.x * GB * PP + t;
        float f  = feat[idx];
        float br = ang[2*idx], bi = ang[2*idx+1];
        nd[0][t] = make_float4(f, br, bi, 1.0f / (br*br + bi*bi));
        spt[0][t] = pt[idx];
    } else if (t >= 64 && t < 64 + PP) {
        const int idx = blockIdx.x * GB * PP + PP + (t - 64);
        float f  = feat[idx];
        float br = ang[2*idx], bi = ang[2*idx+1];
        nd[1][t-64] = make_float4(f, br, bi, 1.0f / (br*br + bi*bi));
        spt[1][t-64] = pt[idx];
    } else if (t >= 128 && t < 148) {
        const int k = t - 128;
        double s = 0.0;
#pragma unroll
        for (int c = 0; c < NCOPY; ++c) s += acc[k * NCOPY + c];
        tmp[k] = s;
    }

    float w1[25], bb1[5], w2[25], bb2[5], w3[25], bb3[5];
#pragma unroll
    for (int i = 0; i < 25; ++i) {
        w1[i] = rfl(W1[i]); w2[i] = rfl(W2[i]); w3[i] = rfl(W3[i]);
    }
#pragma unroll
    for (int i = 0; i < 5; ++i) {
        bb1[i] = rfl(b1[i]); bb2[i] = rfl(b2[i]); bb3[i] = rfl(b3[i]);
    }

    __syncthreads();

    float sc1[5], sh1[5], sc2[5], sh2[5];
#pragma unroll
    for (int o = 0; o < 5; ++o) {
        double mu1  = tmp[o]    * INV_ETOT;
        double var1 = tmp[5+o]  * INV_ETOT - mu1 * mu1;
        float s1 = rfl(g1[o]) * rsqrtf((float)var1 + EPSF);
        sc1[o] = rfl(s1);
        sh1[o] = rfl(rfl(bt1[o]) - (float)mu1 * s1);
        double mu2  = tmp[10+o] * INV_ETOT;
        double var2 = tmp[15+o] * INV_ETOT - mu2 * mu2;
        float s2 = rfl(g2[o]) * rsqrtf((float)var2 + EPSF);
        sc2[o] = rfl(s2);
        sh2[o] = rfl(rfl(bt2[o]) - (float)mu2 * s2);
    }

    const int pi = t / 5;
    const int s  = t - pi*5;

#pragma unroll
    for (int g = 0; g < GB; ++g) {
        float a[5];
#pragma unroll
        for (int k = 0; k < 5; ++k) a[k] = 0.0f;

        if (t < 250) {
            const float4 ni = nd[g][pi];
            const float fi = ni.x, ar = ni.y, ai = ni.z;
#pragma unroll
            for (int q = 0; q < 10; ++q) {
                const float4 nj = nd[g][s*10 + q];
                const float fj = nj.x, br = nj.y, bi = nj.z, inv = nj.w;
                const float dr = (ar*br + ai*bi) * inv;
                const float dm = (ai*br - ar*bi) * inv;
                const float df = fj - fi;
                float h1[5], h2[5];
#pragma unroll
                for (int o = 0; o < 5; ++o) {
                    float y = bb1[o];
                    y = fmaf(w1[o*5+0], fi, y);
                    y = fmaf(w1[o*5+1], fj, y);
                    y = fmaf(w1[o*5+2], df, y);
                    y = fmaf(w1[o*5+3], dr, y);
                    y = fmaf(w1[o*5+4], dm, y);
                    h1[o] = lrelu(fmaf(y, sc1[o], sh1[o]));
                }
#pragma unroll
                for (int o = 0; o < 5; ++o) {
                    float y = bb2[o];
                    y = fmaf(w2[o*5+0], h1[0], y);
                    y = fmaf(w2[o*5+1], h1[1], y);
                    y = fmaf(w2[o*5+2], h1[2], y);
                    y = fmaf(w2[o*5+3], h1[3], y);
                    y = fmaf(w2[o*5+4], h1[4], y);
                    h2[o] = lrelu(fmaf(y, sc2[o], sh2[o]));
                }
#pragma unroll
                for (int o = 0; o < 5; ++o) {
                    float y = bb3[o];
                    y = fmaf(w3[o*5+0], h2[0], y);
                    y = fmaf(w3[o*5+1], h2[1], y);
                    y = fmaf(w3[o*5+2], h2[2], y);
                    y = fmaf(w3[o*5+3], h2[3], y);
                    y = fmaf(w3[o*5+4], h2[4], y);
                    a[o] += y;
                }
            }
#pragma unroll
            for (int c = 0; c < 5; ++c) part[t][c] = a[c];
        }
        __syncthreads();

        if (t < PP) {
            float m[5];
#pragma unroll
            for (int c = 0; c < 5; ++c) {
                m[c] = (part[5*t][c] + part[5*t+1][c] + part[5*t+2][c] +
                        part[5*t+3][c] + part[5*t+4][c]) * 0.02f;
            }
            const int d = (blockIdx.x * GB + g) * PP + t;
            const float4 ni = nd[g][t];
            const float zr = ni.y, zi = ni.z;
            float ss, cc;
            sincosf(6.2831853071795865f * m[4], &ss, &cc);
            float* o = out + (size_t)d * 7;
            o[0] = spt[g][t];
            o[1] = m[0];
            o[2] = m[1];
            o[3] = m[2];
            o[4] = m[3];
            o[5] = cc * zr - ss * zi;
            o[6] = cc * zi + ss * zr;
        }
        __syncthreads();   // protect part[] before next batch overwrites
    }
}

extern "C" void kernel_launch(void* const* d_in, const int* in_sizes, int n_in,
                              void* d_out, int out_size, void* d_ws, size_t ws_size,
                              hipStream_t stream)
{
    const float* pt   = (const float*)d_in[0];
    const float* feat = (const float*)d_in[1];
    const float* ang  = (const float*)d_in[2];
    const float* W1   = (const float*)d_in[3];
    const float* b1   = (const float*)d_in[4];
    const float* g1   = (const float*)d_in[5];
    const float* bt1  = (const float*)d_in[6];
    const float* W2   = (const float*)d_in[7];
    const float* b2   = (const float*)d_in[8];
    const float* g2   = (const float*)d_in[9];
    const float* bt2  = (const float*)d_in[10];
    const float* W3   = (const float*)d_in[11];
    const float* b3   = (const float*)d_in[12];
    // d_in[13] = edge_index: closed-form structure, unused.
    float* out  = (float*)d_out;
    double* acc = (double*)d_ws;   // 1280 doubles

    hipMemsetAsync(d_ws, 0, 1280 * sizeof(double), stream);
    pass1_kernel<<<NBLK, TPB, 0, stream>>>(feat, ang, W1, b1, acc);
    pass2_kernel<<<NBLK, TPB, 0, stream>>>(feat, ang, W1, b1, g1, bt1, W2, b2, acc);
    pass3_kernel<<<NBLK, TPB, 0, stream>>>(pt, feat, ang, W1, b1, g1, bt1, W2, b2,
                                           g2, bt2, W3, b3, acc, out);
}